// Round 5
// baseline (142.925 us; speedup 1.0000x reference)
//
#include <hip/hip_runtime.h>

#define NB  16
#define SQn 2048
#define SKn 2048
#define DHn 64
#define KS  4   // strided key splits

typedef float    f32x4 __attribute__((ext_vector_type(4)));
typedef _Float16 f16x8 __attribute__((ext_vector_type(8)));
typedef _Float16 f16x4 __attribute__((ext_vector_type(4)));
typedef _Float16 f16x2 __attribute__((ext_vector_type(2)));
typedef __fp16   fp16x2 __attribute__((ext_vector_type(2)));  // cvt_pkrtz return type

#define MFMA __builtin_amdgcn_mfma_f32_16x16x32_f16

union H8 { f16x8 v; f16x2 h[4]; };
union H4 { f16x4 v; f16x2 h[2]; };

__device__ __forceinline__ f16x2 pk(float a, float b) {
    fp16x2 r = __builtin_amdgcn_cvt_pkrtz(a, b);
    return __builtin_bit_cast(f16x2, r);
}

__device__ __forceinline__ f16x8 pack8(float a0, float a1, float a2, float a3,
                                       float a4, float a5, float a6, float a7) {
    H8 u;
    u.h[0] = pk(a0, a1);
    u.h[1] = pk(a2, a3);
    u.h[2] = pk(a4, a5);
    u.h[3] = pk(a6, a7);
    return u.v;
}

__device__ __forceinline__ f16x8 cvt8(f32x4 a, f32x4 b) {
    return pack8(a[0], a[1], a[2], a[3], b[0], b[1], b[2], b[3]);
}

// ---------------- prepass: K -> fp16, V -> V^T fp16 ----------------
__global__ __launch_bounds__(256)
void prep_kernel(const float* __restrict__ Kg, const float* __restrict__ Vg,
                 _Float16* __restrict__ Kh, _Float16* __restrict__ VTh)
{
    const int tid = threadIdx.x;
    const int kt  = blockIdx.x;   // 0..31
    const int b   = blockIdx.y;   // 0..15
    const size_t tbase = ((size_t)b * SKn + (size_t)kt * 64) * DHn;

    { // K convert (straight copy)
        const float* s = Kg + tbase + tid * 16;
        f32x4 a0 = *(const f32x4*)(s);
        f32x4 a1 = *(const f32x4*)(s + 4);
        f32x4 a2 = *(const f32x4*)(s + 8);
        f32x4 a3 = *(const f32x4*)(s + 12);
        _Float16* d = Kh + tbase + tid * 16;
        *(f16x8*)d       = cvt8(a0, a1);
        *(f16x8*)(d + 8) = cvt8(a2, a3);
    }
    __shared__ float vt[64][68];
    {
        const int row = tid >> 2, cb = (tid & 3) * 16;
        const float* s = Vg + tbase + row * DHn + cb;
#pragma unroll
        for (int i = 0; i < 4; ++i)
            *(f32x4*)&vt[row][cb + 4 * i] = *(const f32x4*)(s + 4 * i);
    }
    __syncthreads();
    {
        const int d0 = tid >> 2, kc = (tid & 3) * 16;
        f16x8 o0, o1;
#pragma unroll
        for (int j = 0; j < 8; ++j) {
            o0[j] = (_Float16)vt[kc + j][d0];
            o1[j] = (_Float16)vt[kc + 8 + j][d0];
        }
        _Float16* d = VTh + ((size_t)b * DHn + d0) * SKn + (size_t)kt * 64 + kc;
        *(f16x8*)d       = o0;
        *(f16x8*)(d + 8) = o1;
    }
}

// ---------------- main: barrier-free flash attention ----------------
// Each WAVE is independent: 32 queries x one strided key-split. K and V^T
// MFMA fragments loaded register-direct from global (no LDS staging, no
// __syncthreads). LDS only for the per-wave P transpose (C->B layout).
// l computed via ones-row MFMA (C rows replicated => no shuffles).
__global__ __launch_bounds__(256)
void attn_ws(const float* __restrict__ Qg, const _Float16* __restrict__ Kh,
             const _Float16* __restrict__ VTh, const int* __restrict__ VL,
             _Float16* __restrict__ Opart, float* __restrict__ lpart)
{
    const int tid  = threadIdx.x;
    const int wave = tid >> 6;
    const int lane = tid & 63;
    const int l15  = lane & 15;
    const int q4   = lane >> 4;

    const int b  = blockIdx.x & 15;
    const int ks = (blockIdx.x >> 4) & 3;
    const int gq = ((blockIdx.x >> 6) << 2) | wave;   // 0..63 (32-query group)

    const int vl     = VL[b];
    const int ntiles = (vl + 63) >> 6;
    if (ntiles <= ks) return;   // whole block uniform (b, ks shared)

    __shared__ __align__(16) unsigned char smem[16384];
    unsigned char* Pb = smem + wave * 4096;   // per-wave P: [32 q][64 k] f16, swizzled
    const int sw = l15 & 7;

    const float SCALE = 0.18033688011112042f; // log2(e)/sqrt(64)
    const int qbase = gq * 32;

    // ---- Q B-frags: lane holds Q[q=l15][k=c*32+q4*8+j], prescaled ----
    f16x8 qf[2][2];
#pragma unroll
    for (int g = 0; g < 2; ++g) {
        const float* qrow = Qg + ((size_t)b * SQn + qbase + g * 16 + l15) * DHn + q4 * 8;
#pragma unroll
        for (int c = 0; c < 2; ++c) {
            f32x4 x = *(const f32x4*)(qrow + c * 32);
            f32x4 y = *(const f32x4*)(qrow + c * 32 + 4);
            qf[g][c] = pack8(x[0] * SCALE, x[1] * SCALE, x[2] * SCALE, x[3] * SCALE,
                             y[0] * SCALE, y[1] * SCALE, y[2] * SCALE, y[3] * SCALE);
        }
    }

    f16x8 ones;
#pragma unroll
    for (int j = 0; j < 8; ++j) ones[j] = (_Float16)1.0f;

    f32x4 O[2][4];
#pragma unroll
    for (int g = 0; g < 2; ++g)
#pragma unroll
        for (int t = 0; t < 4; ++t) O[g][t] = (f32x4){0.f, 0.f, 0.f, 0.f};
    f32x4 lC[2];
    lC[0] = (f32x4){0.f, 0.f, 0.f, 0.f};
    lC[1] = (f32x4){0.f, 0.f, 0.f, 0.f};

    const _Float16* Kp  = Kh + ((size_t)b * SKn + (size_t)ks * 64) * DHn;
    const _Float16* VTb = VTh + (size_t)b * DHn * SKn + (size_t)ks * 64;

    for (int kt = ks; kt < ntiles; kt += KS) {
        const _Float16* Kt = Kp + (size_t)(kt - ks) * DHn * 64;
        const _Float16* Vt = VTb + (size_t)(kt - ks) * 64;

        // ---- K A-frags: lane holds K[key=16t+l15][k=c*32+q4*8+j] ----
        f16x8 kf[4][2];
#pragma unroll
        for (int t = 0; t < 4; ++t)
#pragma unroll
            for (int c = 0; c < 2; ++c)
                kf[t][c] = *(const f16x8*)(Kt + (16 * t + l15) * DHn + c * 32 + q4 * 8);

        // ---- V^T A-frags: lane holds VT[d=16t2+l15][key=c2*32+q4*8+j] ----
        f16x8 vf[4][2];
#pragma unroll
        for (int t2 = 0; t2 < 4; ++t2)
#pragma unroll
            for (int c2 = 0; c2 < 2; ++c2)
                vf[t2][c2] = *(const f16x8*)(Vt + (size_t)(16 * t2 + l15) * SKn + c2 * 32 + q4 * 8);

        // ---- S^T = K Q^T : C row=key=16t+4q4+reg, col=q=l15 ----
        f32x4 st[2][4];
#pragma unroll
        for (int g = 0; g < 2; ++g)
#pragma unroll
            for (int t = 0; t < 4; ++t) st[g][t] = (f32x4){0.f, 0.f, 0.f, 0.f};
#pragma unroll
        for (int t = 0; t < 4; ++t)
#pragma unroll
            for (int c = 0; c < 2; ++c) {
                st[0][t] = MFMA(kf[t][c], qf[0][c], st[0][t], 0, 0, 0);
                st[1][t] = MFMA(kf[t][c], qf[1][c], st[1][t], 0, 0, 0);
            }

        // ---- p = exp2(s'), mask last partial tile, pack -> P buffer ----
        const bool lastt = (kt == ntiles - 1) && (vl & 63);
#pragma unroll
        for (int g = 0; g < 2; ++g) {
            unsigned char* pdst = Pb + (g * 16 + l15) * 128 + (q4 & 1) * 8;
#pragma unroll
            for (int t = 0; t < 4; ++t) {
                float p0 = __builtin_amdgcn_exp2f(st[g][t][0]);
                float p1 = __builtin_amdgcn_exp2f(st[g][t][1]);
                float p2 = __builtin_amdgcn_exp2f(st[g][t][2]);
                float p3 = __builtin_amdgcn_exp2f(st[g][t][3]);
                if (lastt) {
                    const int kb0 = kt * 64 + 16 * t + 4 * q4;
                    p0 = (kb0 + 0 < vl) ? p0 : 0.f;
                    p1 = (kb0 + 1 < vl) ? p1 : 0.f;
                    p2 = (kb0 + 2 < vl) ? p2 : 0.f;
                    p3 = (kb0 + 3 < vl) ? p3 : 0.f;
                }
                H4 w;
                w.h[0] = pk(p0, p1);
                w.h[1] = pk(p2, p3);
                *(f16x4*)(pdst + (((2 * t + (q4 >> 1)) ^ sw) * 16)) = w.v;
            }
        }
        asm volatile("" ::: "memory"); // same-wave DS ordering; stop compiler reorder

        // ---- P B-frags: lane holds P[k=c2*32+q4*8+j][q=l15] ----
        f16x8 pf[2][2];
#pragma unroll
        for (int g = 0; g < 2; ++g) {
            const unsigned char* psrc = Pb + (g * 16 + l15) * 128;
            pf[g][0] = *(const f16x8*)(psrc + ((q4 ^ sw) * 16));
            pf[g][1] = *(const f16x8*)(psrc + (((4 | q4) ^ sw) * 16));
        }

        // ---- O^T += V^T P : C row=d=16t2+4q4+reg, col=q=l15 ----
#pragma unroll
        for (int t2 = 0; t2 < 4; ++t2)
#pragma unroll
            for (int c2 = 0; c2 < 2; ++c2) {
                O[0][t2] = MFMA(vf[t2][c2], pf[0][c2], O[0][t2], 0, 0, 0);
                O[1][t2] = MFMA(vf[t2][c2], pf[1][c2], O[1][t2], 0, 0, 0);
            }
        // ---- l += 1^T P (rows of C all equal l[q]) ----
#pragma unroll
        for (int c2 = 0; c2 < 2; ++c2) {
            lC[0] = MFMA(ones, pf[0][c2], lC[0], 0, 0, 0);
            lC[1] = MFMA(ones, pf[1][c2], lC[1], 0, 0, 0);
        }
    }

    // ---- epilogue: write unnormalized O (f16) + l (f32) to ws ----
#pragma unroll
    for (int g = 0; g < 2; ++g) {
        const size_t qrow = (size_t)ks * (NB * SQn) + (size_t)b * SQn + qbase + g * 16 + l15;
        if (q4 == 0) lpart[qrow] = lC[g][0];
        _Float16* od = Opart + qrow * DHn;
#pragma unroll
        for (int t2 = 0; t2 < 4; ++t2) {
            H4 w;
            w.h[0] = pk(O[g][t2][0], O[g][t2][1]);
            w.h[1] = pk(O[g][t2][2], O[g][t2][3]);
            *(f16x4*)(od + 16 * t2 + 4 * q4) = w.v;
        }
    }
}

// ---------------- merge: out = sum_s Opart / sum_s l ----------------
__global__ __launch_bounds__(256)
void merge_kernel(const _Float16* __restrict__ Op, const float* __restrict__ lp,
                  const int* __restrict__ VL, float* __restrict__ Og)
{
    const int i   = blockIdx.x * 256 + threadIdx.x;  // over B*SQ*DH/4
    const int row = i >> 4;                          // b*2048 + q
    const int dc  = (i & 15) * 4;
    const int b   = row >> 11;
    const int ntiles = (VL[b] + 63) >> 6;
    const int nact   = ntiles < KS ? ntiles : KS;

    f32x4 acc = (f32x4){0.f, 0.f, 0.f, 0.f};
    float l = 0.f;
    for (int s = 0; s < nact; ++s) {
        f16x4 h = *(const f16x4*)(Op + ((size_t)s * (NB * SQn) + row) * DHn + dc);
        acc[0] += (float)h[0]; acc[1] += (float)h[1];
        acc[2] += (float)h[2]; acc[3] += (float)h[3];
        l += lp[(size_t)s * (NB * SQn) + row];
    }
    const float inv = 1.f / l;
    acc *= inv;
    *(f32x4*)(Og + (size_t)row * DHn + dc) = acc;
}

// ---------------- fallback (only if ws too small): R1 fused kernel ----------------
__global__ __launch_bounds__(256, 2)
void attn_fwd(const float* __restrict__ Qg, const float* __restrict__ Kg,
              const float* __restrict__ Vg, const int* __restrict__ VL,
              float* __restrict__ Og)
{
    const int tid  = threadIdx.x;
    const int wave = tid >> 6;
    const int lane = tid & 63;
    const int l15  = lane & 15;
    const int q4   = lane >> 4;
    const int b  = blockIdx.x & 15;
    const int qb = blockIdx.x >> 4;
    __shared__ __align__(16) unsigned char smemf[8192 + 8192 + 4 * 2048];
    unsigned char* Klds  = smemf;
    unsigned char* VTlds = smemf + 8192;
    unsigned char* Plds  = smemf + 16384 + wave * 2048;
    const int vl = VL[b];
    const int ntiles = (vl + 63) >> 6;
    const float SCALE = 0.18033688011112042f;
    f16x8 qfr[2];
    {
        const float* qrow = Qg + ((size_t)b * SQn + (size_t)qb * 64 + wave * 16 + l15) * DHn;
#pragma unroll
        for (int c = 0; c < 2; ++c) {
            const float* s = qrow + c * 32 + q4 * 8;
            f32x4 a = *(const f32x4*)s;
            f32x4 b2 = *(const f32x4*)(s + 4);
            a *= SCALE; b2 *= SCALE;
            qfr[c] = cvt8(a, b2);
        }
    }
    f32x4 O[4];
#pragma unroll
    for (int t = 0; t < 4; ++t) O[t] = (f32x4){0.f, 0.f, 0.f, 0.f};
    float m_i[4] = {-3e38f, -3e38f, -3e38f, -3e38f};
    float l_i[4] = {0.f, 0.f, 0.f, 0.f};
    for (int kt = 0; kt < ntiles; ++kt) {
        const int k0 = kt * 64;
#pragma unroll
        for (int i = 0; i < 2; ++i) {
            int g8 = tid + i * 256;
            int row = g8 >> 3, g = g8 & 7;
            const float* s = Kg + ((size_t)b * SKn + k0 + row) * DHn + g * 8;
            f32x4 a = *(const f32x4*)s;
            f32x4 c4 = *(const f32x4*)(s + 4);
            *(f16x8*)(Klds + row * 128 + ((g ^ (row & 7)) * 16)) = cvt8(a, c4);
        }
        {
            int key = tid & 63, dg = tid >> 6;
            const float* s = Vg + ((size_t)b * SKn + k0 + key) * DHn + dg * 16;
            int swz = key >> 3;
            int koff = (key & 7) * 2;
#pragma unroll
            for (int i = 0; i < 4; ++i) {
                f32x4 v4 = *(const f32x4*)(s + i * 4);
#pragma unroll
                for (int j = 0; j < 4; ++j) {
                    int d = dg * 16 + i * 4 + j;
                    *(_Float16*)(VTlds + d * 128 + ((swz ^ (d & 7)) * 16) + koff) = (_Float16)v4[j];
                }
            }
        }
        __syncthreads();
        f32x4 accs[4];
#pragma unroll
        for (int t = 0; t < 4; ++t) accs[t] = (f32x4){0.f, 0.f, 0.f, 0.f};
#pragma unroll
        for (int t = 0; t < 4; ++t) {
            int row = t * 16 + l15;
#pragma unroll
            for (int c = 0; c < 2; ++c) {
                f16x8 kf = *(const f16x8*)(Klds + row * 128 + ((((c << 2) + q4) ^ (l15 & 7)) * 16));
                accs[t] = MFMA(qfr[c], kf, accs[t], 0, 0, 0);
            }
        }
        if (k0 + 64 > vl) {
#pragma unroll
            for (int t = 0; t < 4; ++t)
                if (k0 + t * 16 + l15 >= vl) accs[t] = (f32x4){-1e30f, -1e30f, -1e30f, -1e30f};
        }
        float al[4];
#pragma unroll
        for (int rr = 0; rr < 4; ++rr) {
            float v = fmaxf(fmaxf(accs[0][rr], accs[1][rr]), fmaxf(accs[2][rr], accs[3][rr]));
            v = fmaxf(v, __shfl_xor(v, 1));
            v = fmaxf(v, __shfl_xor(v, 2));
            v = fmaxf(v, __shfl_xor(v, 4));
            v = fmaxf(v, __shfl_xor(v, 8));
            float mnew = fmaxf(m_i[rr], v);
            al[rr] = __builtin_amdgcn_exp2f(m_i[rr] - mnew);
            m_i[rr] = mnew;
        }
#pragma unroll
        for (int rr = 0; rr < 4; ++rr) {
            float s0 = 0.f;
#pragma unroll
            for (int t = 0; t < 4; ++t) {
                float p = __builtin_amdgcn_exp2f(accs[t][rr] - m_i[rr]);
                accs[t][rr] = p;
                s0 += p;
            }
            s0 += __shfl_xor(s0, 1);
            s0 += __shfl_xor(s0, 2);
            s0 += __shfl_xor(s0, 4);
            s0 += __shfl_xor(s0, 8);
            l_i[rr] = l_i[rr] * al[rr] + s0;
            O[0][rr] *= al[rr]; O[1][rr] *= al[rr]; O[2][rr] *= al[rr]; O[3][rr] *= al[rr];
        }
#pragma unroll
        for (int rr = 0; rr < 4; ++rr) {
            int row = q4 * 4 + rr;
            int swz = row & 7;
#pragma unroll
            for (int t = 0; t < 4; ++t) {
                int g = t * 2 + (l15 >> 3);
                *(_Float16*)(Plds + row * 128 + ((g ^ swz) * 16) + (l15 & 7) * 2) = (_Float16)accs[t][rr];
            }
        }
        asm volatile("" ::: "memory");
        f16x8 pfr[2];
        pfr[0] = *(const f16x8*)(Plds + l15 * 128 + ((q4 ^ (l15 & 7)) * 16));
        pfr[1] = *(const f16x8*)(Plds + l15 * 128 + (((4 + q4) ^ (l15 & 7)) * 16));
#pragma unroll
        for (int t2 = 0; t2 < 4; ++t2) {
            int d = t2 * 16 + l15;
#pragma unroll
            for (int c2 = 0; c2 < 2; ++c2) {
                f16x8 vf = *(const f16x8*)(VTlds + d * 128 + ((((c2 << 2) + q4) ^ (l15 & 7)) * 16));
                O[t2] = MFMA(pfr[c2], vf, O[t2], 0, 0, 0);
            }
        }
        __syncthreads();
    }
    float inv[4];
#pragma unroll
    for (int rr = 0; rr < 4; ++rr) inv[rr] = 1.f / l_i[rr];
    float* orow = Og + ((size_t)b * SQn + (size_t)qb * 64 + wave * 16 + q4 * 4) * DHn;
#pragma unroll
    for (int rr = 0; rr < 4; ++rr)
#pragma unroll
        for (int t2 = 0; t2 < 4; ++t2)
            orow[rr * DHn + t2 * 16 + l15] = O[t2][rr] * inv[rr];
}

extern "C" void kernel_launch(void* const* d_in, const int* in_sizes, int n_in,
                              void* d_out, int out_size, void* d_ws, size_t ws_size,
                              hipStream_t stream) {
    (void)in_sizes; (void)n_in; (void)out_size;
    const float* Q = (const float*)d_in[0];
    const float* K = (const float*)d_in[1];
    const float* V = (const float*)d_in[2];
    const int*  VLp = (const int*)d_in[3];
    float* O = (float*)d_out;

    const size_t kv_elems = (size_t)NB * SKn * DHn;          // 2M
    const size_t rows     = (size_t)NB * SQn;                // 32768
    // ws: Kh f16 | VTh f16 | Opart f16 (KS*rows*64) | lpart f32 (KS*rows)
    const size_t off_Kh = 0;
    const size_t off_VT = kv_elems * sizeof(_Float16);
    const size_t off_Op = off_VT + kv_elems * sizeof(_Float16);
    const size_t off_lp = off_Op + (size_t)KS * rows * DHn * sizeof(_Float16);
    const size_t need   = off_lp + (size_t)KS * rows * sizeof(float);

    if (ws_size >= need) {
        _Float16* Kh    = (_Float16*)((char*)d_ws + off_Kh);
        _Float16* VTh   = (_Float16*)((char*)d_ws + off_VT);
        _Float16* Opart = (_Float16*)((char*)d_ws + off_Op);
        float* lpart    = (float*)((char*)d_ws + off_lp);
        hipLaunchKernelGGL(prep_kernel, dim3(SKn / 64, NB), dim3(256), 0, stream, K, V, Kh, VTh);
        // grid: 16 b x 4 ks x 16 qgroup128 = 1024 blocks x 4 independent waves
        hipLaunchKernelGGL(attn_ws, dim3(NB * KS * (SQn / 128)), dim3(256), 0, stream,
                           Q, Kh, VTh, VLp, Opart, lpart);
        hipLaunchKernelGGL(merge_kernel, dim3((NB * SQn * DHn / 4) / 256), dim3(256), 0, stream,
                           Opart, lpart, VLp, O);
    } else {
        hipLaunchKernelGGL(attn_fwd, dim3(NB * (SQn / 64)), dim3(256), 0, stream, Q, K, V, VLp, O);
    }
}

// Round 7
// 103.555 us; speedup vs baseline: 1.3802x; 1.3802x over previous
//
#include <hip/hip_runtime.h>

#define NB  16
#define SQn 2048
#define SKn 2048
#define DHn 64
#define KS  4   // strided key splits

typedef float    f32x4 __attribute__((ext_vector_type(4)));
typedef _Float16 f16x8 __attribute__((ext_vector_type(8)));
typedef _Float16 f16x4 __attribute__((ext_vector_type(4)));
typedef _Float16 f16x2 __attribute__((ext_vector_type(2)));
typedef __fp16   fp16x2 __attribute__((ext_vector_type(2)));  // cvt_pkrtz return type

#define MFMA __builtin_amdgcn_mfma_f32_16x16x32_f16

union H8 { f16x8 v; f16x2 h[4]; };
union H4 { f16x4 v; f16x2 h[2]; };

__device__ __forceinline__ f16x2 pk(float a, float b) {
    fp16x2 r = __builtin_amdgcn_cvt_pkrtz(a, b);
    return __builtin_bit_cast(f16x2, r);
}

__device__ __forceinline__ f16x8 pack8(float a0, float a1, float a2, float a3,
                                       float a4, float a5, float a6, float a7) {
    H8 u;
    u.h[0] = pk(a0, a1);
    u.h[1] = pk(a2, a3);
    u.h[2] = pk(a4, a5);
    u.h[3] = pk(a6, a7);
    return u.v;
}

__device__ __forceinline__ f16x8 cvt8(f32x4 a, f32x4 b) {
    return pack8(a[0], a[1], a[2], a[3], b[0], b[1], b[2], b[3]);
}

// stage 16B/lane: global -> LDS (HW dest = wave-uniform base + lane*16)
__device__ __forceinline__ void stage16(const void* g, unsigned char* base) {
    __builtin_amdgcn_global_load_lds(
        (const __attribute__((address_space(1))) unsigned int*)g,
        (__attribute__((address_space(3))) unsigned int*)base,
        16, 0, 0);
}

// ---------------- prepass: K -> fp16, V -> V^T fp16 ----------------
__global__ __launch_bounds__(256)
void prep_kernel(const float* __restrict__ Kg, const float* __restrict__ Vg,
                 _Float16* __restrict__ Kh, _Float16* __restrict__ VTh)
{
    const int tid = threadIdx.x;
    const int kt  = blockIdx.x;   // 0..31
    const int b   = blockIdx.y;   // 0..15
    const size_t tbase = ((size_t)b * SKn + (size_t)kt * 64) * DHn;

    { // K convert (straight copy)
        const float* s = Kg + tbase + tid * 16;
        f32x4 a0 = *(const f32x4*)(s);
        f32x4 a1 = *(const f32x4*)(s + 4);
        f32x4 a2 = *(const f32x4*)(s + 8);
        f32x4 a3 = *(const f32x4*)(s + 12);
        _Float16* d = Kh + tbase + tid * 16;
        *(f16x8*)d       = cvt8(a0, a1);
        *(f16x8*)(d + 8) = cvt8(a2, a3);
    }
    __shared__ float vt[64][68];
    {
        const int row = tid >> 2, cb = (tid & 3) * 16;
        const float* s = Vg + tbase + row * DHn + cb;
#pragma unroll
        for (int i = 0; i < 4; ++i)
            *(f32x4*)&vt[row][cb + 4 * i] = *(const f32x4*)(s + 4 * i);
    }
    __syncthreads();
    {
        const int d0 = tid >> 2, kc = (tid & 3) * 16;
        f16x8 o0, o1;
#pragma unroll
        for (int j = 0; j < 8; ++j) {
            o0[j] = (_Float16)vt[kc + j][d0];
            o1[j] = (_Float16)vt[kc + 8 + j][d0];
        }
        _Float16* d = VTh + ((size_t)b * DHn + d0) * SKn + (size_t)kt * 64 + kc;
        *(f16x8*)d       = o0;
        *(f16x8*)(d + 8) = o1;
    }
}

// ---------------- main: double-buffered shared-staging flash attention ----------------
// Block: 8 waves = 512 thr, 256 queries, strided key-split ks. Per round all
// 8 waves compute ONE 64-key tile (staged once to LDS, 8x reuse). Tile r+1
// is staged into the idle buffer right after the barrier, so the
// vmcnt(0)-before-barrier drain lands after the compute phase (latency hidden).
// LDS: 2x16KB K/V dbuf + 8x4KB per-wave P = 64KB -> 2 blocks/CU.
__global__ __launch_bounds__(512, 4)
void attn_db(const float* __restrict__ Qg, const _Float16* __restrict__ Kh,
             const _Float16* __restrict__ VTh, const int* __restrict__ VL,
             _Float16* __restrict__ Opart, float* __restrict__ lpart)
{
    const int tid  = threadIdx.x;
    const int wave = tid >> 6;
    const int lane = tid & 63;
    const int l15  = lane & 15;
    const int q4   = lane >> 4;

    const int b  = blockIdx.x & 15;
    const int ks = (blockIdx.x >> 4) & 3;
    const int qb = blockIdx.x >> 6;       // 0..7

    const int vl     = VL[b];
    const int ntiles = (vl + 63) >> 6;
    if (ntiles <= ks) return;             // block-uniform (b, ks shared)
    const int nrounds = (ntiles - ks + KS - 1) / KS;

    __shared__ __align__(16) unsigned char smem[2 * 16384 + 8 * 4096];  // 64 KB
    unsigned char* Pb = smem + 32768 + wave * 4096;   // per-wave P: [32 q][64 k] f16
    const int sw = l15 & 7;

    const float SCALE = 0.18033688011112042f; // log2(e)/sqrt(64)
    const int qbase = qb * 256 + wave * 32;

    // ---- Q B-frags: lane holds Q[q=l15][k=c*32+q4*8+j], prescaled ----
    f16x8 qf[2][2];
#pragma unroll
    for (int g = 0; g < 2; ++g) {
        const float* qrow = Qg + ((size_t)b * SQn + qbase + g * 16 + l15) * DHn + q4 * 8;
#pragma unroll
        for (int c = 0; c < 2; ++c) {
            f32x4 x = *(const f32x4*)(qrow + c * 32);
            f32x4 y = *(const f32x4*)(qrow + c * 32 + 4);
            qf[g][c] = pack8(x[0] * SCALE, x[1] * SCALE, x[2] * SCALE, x[3] * SCALE,
                             y[0] * SCALE, y[1] * SCALE, y[2] * SCALE, y[3] * SCALE);
        }
    }

    f16x8 ones;
#pragma unroll
    for (int j = 0; j < 8; ++j) ones[j] = (_Float16)1.0f;

    f32x4 O[2][4];
#pragma unroll
    for (int g = 0; g < 2; ++g)
#pragma unroll
        for (int t = 0; t < 4; ++t) O[g][t] = (f32x4){0.f, 0.f, 0.f, 0.f};
    f32x4 lC[2];
    lC[0] = (f32x4){0.f, 0.f, 0.f, 0.f};
    lC[1] = (f32x4){0.f, 0.f, 0.f, 0.f};

    const _Float16* KhB = Kh + (size_t)b * SKn * DHn;
    const _Float16* VTB = VTh + (size_t)b * DHn * SKn;

    // staging geometry: slot = wave*64+lane covers 512 granule-slots/tile
    const int slot = wave * 64 + lane;
    const int srow = slot >> 3;
    const int sgl  = (slot & 7) ^ (srow & 7);

    // prologue: stage tile ks into buf0
    stage16(KhB + (size_t)(ks * 64 + srow) * DHn + sgl * 8, smem + wave * 1024);
    stage16(VTB + (size_t)srow * SKn + ks * 64 + sgl * 8, smem + 8192 + wave * 1024);

    for (int r = 0; r < nrounds; ++r) {
        __syncthreads();   // drains pending staging (vmcnt0) + wave sync
        const int cur = r & 1;
        if (r + 1 < nrounds) {   // stage next tile into idle buffer (hidden by compute)
            const int ktn = ks + (r + 1) * KS;
            unsigned char* nb = smem + (1 - cur) * 16384;
            stage16(KhB + (size_t)(ktn * 64 + srow) * DHn + sgl * 8, nb + wave * 1024);
            stage16(VTB + (size_t)srow * SKn + ktn * 64 + sgl * 8, nb + 8192 + wave * 1024);
        }
        const int kt = ks + r * KS;
        const unsigned char* Kb = smem + cur * 16384;
        const unsigned char* Vb = Kb + 8192;

        // ---- S^T = K Q^T : C row=key=16t+4q4+reg, col=q=l15 ----
        f32x4 st[2][4];
#pragma unroll
        for (int g = 0; g < 2; ++g)
#pragma unroll
            for (int t = 0; t < 4; ++t) st[g][t] = (f32x4){0.f, 0.f, 0.f, 0.f};
#pragma unroll
        for (int t = 0; t < 4; ++t) {
            const int row = 16 * t + l15;
#pragma unroll
            for (int c = 0; c < 2; ++c) {
                f16x8 kf = *(const f16x8*)(Kb + row * 128 + ((((c << 2) | q4) ^ sw) * 16));
                st[0][t] = MFMA(kf, qf[0][c], st[0][t], 0, 0, 0);
                st[1][t] = MFMA(kf, qf[1][c], st[1][t], 0, 0, 0);
            }
        }

        // ---- p = exp2(s'), mask last partial tile, pack -> P buffer ----
        const bool lastt = (kt == ntiles - 1) && (vl & 63);
#pragma unroll
        for (int g = 0; g < 2; ++g) {
            unsigned char* pdst = Pb + (g * 16 + l15) * 128 + (q4 & 1) * 8;
#pragma unroll
            for (int t = 0; t < 4; ++t) {
                float p0 = __builtin_amdgcn_exp2f(st[g][t][0]);
                float p1 = __builtin_amdgcn_exp2f(st[g][t][1]);
                float p2 = __builtin_amdgcn_exp2f(st[g][t][2]);
                float p3 = __builtin_amdgcn_exp2f(st[g][t][3]);
                if (lastt) {
                    const int kb0 = kt * 64 + 16 * t + 4 * q4;
                    p0 = (kb0 + 0 < vl) ? p0 : 0.f;
                    p1 = (kb0 + 1 < vl) ? p1 : 0.f;
                    p2 = (kb0 + 2 < vl) ? p2 : 0.f;
                    p3 = (kb0 + 3 < vl) ? p3 : 0.f;
                }
                H4 w;
                w.h[0] = pk(p0, p1);
                w.h[1] = pk(p2, p3);
                *(f16x4*)(pdst + (((2 * t + (q4 >> 1)) ^ sw) * 16)) = w.v;
            }
        }
        asm volatile("" ::: "memory"); // same-wave DS in-order: stores before loads

        // ---- P B-frags: lane holds P[k=c2*32+q4*8+j][q=l15] ----
        f16x8 pf[2][2];
#pragma unroll
        for (int g = 0; g < 2; ++g) {
            const unsigned char* psrc = Pb + (g * 16 + l15) * 128;
            pf[g][0] = *(const f16x8*)(psrc + ((q4 ^ sw) * 16));
            pf[g][1] = *(const f16x8*)(psrc + (((4 | q4) ^ sw) * 16));
        }

        // ---- O^T += V^T P : C row=d=16t2+4q4+reg, col=q=l15 ----
#pragma unroll
        for (int t2 = 0; t2 < 4; ++t2) {
            const int row = 16 * t2 + l15;
#pragma unroll
            for (int c2 = 0; c2 < 2; ++c2) {
                f16x8 vf = *(const f16x8*)(Vb + row * 128 + ((((c2 << 2) | q4) ^ sw) * 16));
                O[0][t2] = MFMA(vf, pf[0][c2], O[0][t2], 0, 0, 0);
                O[1][t2] = MFMA(vf, pf[1][c2], O[1][t2], 0, 0, 0);
            }
        }
        // ---- l += 1^T P (C rows replicated => per-lane scalar l) ----
#pragma unroll
        for (int c2 = 0; c2 < 2; ++c2) {
            lC[0] = MFMA(ones, pf[0][c2], lC[0], 0, 0, 0);
            lC[1] = MFMA(ones, pf[1][c2], lC[1], 0, 0, 0);
        }
    }

    // ---- epilogue: write unnormalized O (f16) + l (f32) to ws ----
#pragma unroll
    for (int g = 0; g < 2; ++g) {
        const size_t qrow = (size_t)ks * (NB * SQn) + (size_t)b * SQn + qbase + g * 16 + l15;
        if (q4 == 0) lpart[qrow] = lC[g][0];
        _Float16* od = Opart + qrow * DHn;
#pragma unroll
        for (int t2 = 0; t2 < 4; ++t2) {
            H4 w;
            w.h[0] = pk(O[g][t2][0], O[g][t2][1]);
            w.h[1] = pk(O[g][t2][2], O[g][t2][3]);
            *(f16x4*)(od + 16 * t2 + 4 * q4) = w.v;
        }
    }
}

// ---------------- merge: out = sum_s Opart / sum_s l ----------------
__global__ __launch_bounds__(256)
void merge_kernel(const _Float16* __restrict__ Op, const float* __restrict__ lp,
                  const int* __restrict__ VL, float* __restrict__ Og)
{
    const int i   = blockIdx.x * 256 + threadIdx.x;  // over B*SQ*DH/4
    const int row = i >> 4;                          // b*2048 + q
    const int dc  = (i & 15) * 4;
    const int b   = row >> 11;
    const int ntiles = (VL[b] + 63) >> 6;
    const int nact   = ntiles < KS ? ntiles : KS;

    f32x4 acc = (f32x4){0.f, 0.f, 0.f, 0.f};
    float l = 0.f;
    for (int s = 0; s < nact; ++s) {
        f16x4 h = *(const f16x4*)(Op + ((size_t)s * (NB * SQn) + row) * DHn + dc);
        acc[0] += (float)h[0]; acc[1] += (float)h[1];
        acc[2] += (float)h[2]; acc[3] += (float)h[3];
        l += lp[(size_t)s * (NB * SQn) + row];
    }
    const float inv = 1.f / l;
    acc *= inv;
    *(f32x4*)(Og + (size_t)row * DHn + dc) = acc;
}

// ---------------- fallback (only if ws too small): R1 fused kernel ----------------
__global__ __launch_bounds__(256, 2)
void attn_fwd(const float* __restrict__ Qg, const float* __restrict__ Kg,
              const float* __restrict__ Vg, const int* __restrict__ VL,
              float* __restrict__ Og)
{
    const int tid  = threadIdx.x;
    const int wave = tid >> 6;
    const int lane = tid & 63;
    const int l15  = lane & 15;
    const int q4   = lane >> 4;
    const int b  = blockIdx.x & 15;
    const int qb = blockIdx.x >> 4;
    __shared__ __align__(16) unsigned char smemf[8192 + 8192 + 4 * 2048];
    unsigned char* Klds  = smemf;
    unsigned char* VTlds = smemf + 8192;
    unsigned char* Plds  = smemf + 16384 + wave * 2048;
    const int vl = VL[b];
    const int ntiles = (vl + 63) >> 6;
    const float SCALE = 0.18033688011112042f;
    f16x8 qfr[2];
    {
        const float* qrow = Qg + ((size_t)b * SQn + (size_t)qb * 64 + wave * 16 + l15) * DHn;
#pragma unroll
        for (int c = 0; c < 2; ++c) {
            const float* s = qrow + c * 32 + q4 * 8;
            f32x4 a = *(const f32x4*)s;
            f32x4 b2 = *(const f32x4*)(s + 4);
            a *= SCALE; b2 *= SCALE;
            qfr[c] = cvt8(a, b2);
        }
    }
    f32x4 O[4];
#pragma unroll
    for (int t = 0; t < 4; ++t) O[t] = (f32x4){0.f, 0.f, 0.f, 0.f};
    float m_i[4] = {-3e38f, -3e38f, -3e38f, -3e38f};
    float l_i[4] = {0.f, 0.f, 0.f, 0.f};
    for (int kt = 0; kt < ntiles; ++kt) {
        const int k0 = kt * 64;
#pragma unroll
        for (int i = 0; i < 2; ++i) {
            int g8 = tid + i * 256;
            int row = g8 >> 3, g = g8 & 7;
            const float* s = Kg + ((size_t)b * SKn + k0 + row) * DHn + g * 8;
            f32x4 a = *(const f32x4*)s;
            f32x4 c4 = *(const f32x4*)(s + 4);
            *(f16x8*)(Klds + row * 128 + ((g ^ (row & 7)) * 16)) = cvt8(a, c4);
        }
        {
            int key = tid & 63, dg = tid >> 6;
            const float* s = Vg + ((size_t)b * SKn + k0 + key) * DHn + dg * 16;
            int swz = key >> 3;
            int koff = (key & 7) * 2;
#pragma unroll
            for (int i = 0; i < 4; ++i) {
                f32x4 v4 = *(const f32x4*)(s + i * 4);
#pragma unroll
                for (int j = 0; j < 4; ++j) {
                    int d = dg * 16 + i * 4 + j;
                    *(_Float16*)(VTlds + d * 128 + ((swz ^ (d & 7)) * 16) + koff) = (_Float16)v4[j];
                }
            }
        }
        __syncthreads();
        f32x4 accs[4];
#pragma unroll
        for (int t = 0; t < 4; ++t) accs[t] = (f32x4){0.f, 0.f, 0.f, 0.f};
#pragma unroll
        for (int t = 0; t < 4; ++t) {
            int row = t * 16 + l15;
#pragma unroll
            for (int c = 0; c < 2; ++c) {
                f16x8 kf = *(const f16x8*)(Klds + row * 128 + ((((c << 2) + q4) ^ (l15 & 7)) * 16));
                accs[t] = MFMA(qfr[c], kf, accs[t], 0, 0, 0);
            }
        }
        if (k0 + 64 > vl) {
#pragma unroll
            for (int t = 0; t < 4; ++t)
                if (k0 + t * 16 + l15 >= vl) accs[t] = (f32x4){-1e30f, -1e30f, -1e30f, -1e30f};
        }
        float al[4];
#pragma unroll
        for (int rr = 0; rr < 4; ++rr) {
            float v = fmaxf(fmaxf(accs[0][rr], accs[1][rr]), fmaxf(accs[2][rr], accs[3][rr]));
            v = fmaxf(v, __shfl_xor(v, 1));
            v = fmaxf(v, __shfl_xor(v, 2));
            v = fmaxf(v, __shfl_xor(v, 4));
            v = fmaxf(v, __shfl_xor(v, 8));
            float mnew = fmaxf(m_i[rr], v);
            al[rr] = __builtin_amdgcn_exp2f(m_i[rr] - mnew);
            m_i[rr] = mnew;
        }
#pragma unroll
        for (int rr = 0; rr < 4; ++rr) {
            float s0 = 0.f;
#pragma unroll
            for (int t = 0; t < 4; ++t) {
                float p = __builtin_amdgcn_exp2f(accs[t][rr] - m_i[rr]);
                accs[t][rr] = p;
                s0 += p;
            }
            s0 += __shfl_xor(s0, 1);
            s0 += __shfl_xor(s0, 2);
            s0 += __shfl_xor(s0, 4);
            s0 += __shfl_xor(s0, 8);
            l_i[rr] = l_i[rr] * al[rr] + s0;
            O[0][rr] *= al[rr]; O[1][rr] *= al[rr]; O[2][rr] *= al[rr]; O[3][rr] *= al[rr];
        }
#pragma unroll
        for (int rr = 0; rr < 4; ++rr) {
            int row = q4 * 4 + rr;
            int swz = row & 7;
#pragma unroll
            for (int t = 0; t < 4; ++t) {
                int g = t * 2 + (l15 >> 3);
                *(_Float16*)(Plds + row * 128 + ((g ^ swz) * 16) + (l15 & 7) * 2) = (_Float16)accs[t][rr];
            }
        }
        asm volatile("" ::: "memory");
        f16x8 pfr[2];
        pfr[0] = *(const f16x8*)(Plds + l15 * 128 + ((q4 ^ (l15 & 7)) * 16));
        pfr[1] = *(const f16x8*)(Plds + l15 * 128 + (((4 + q4) ^ (l15 & 7)) * 16));
#pragma unroll
        for (int t2 = 0; t2 < 4; ++t2) {
            int d = t2 * 16 + l15;
#pragma unroll
            for (int c2 = 0; c2 < 2; ++c2) {
                f16x8 vf = *(const f16x8*)(VTlds + d * 128 + ((((c2 << 2) + q4) ^ (l15 & 7)) * 16));
                O[t2] = MFMA(pfr[c2], vf, O[t2], 0, 0, 0);
            }
        }
        __syncthreads();
    }
    float inv[4];
#pragma unroll
    for (int rr = 0; rr < 4; ++rr) inv[rr] = 1.f / l_i[rr];
    float* orow = Og + ((size_t)b * SQn + (size_t)qb * 64 + wave * 16 + q4 * 4) * DHn;
#pragma unroll
    for (int rr = 0; rr < 4; ++rr)
#pragma unroll
        for (int t2 = 0; t2 < 4; ++t2)
            orow[rr * DHn + t2 * 16 + l15] = O[t2][rr] * inv[rr];
}

extern "C" void kernel_launch(void* const* d_in, const int* in_sizes, int n_in,
                              void* d_out, int out_size, void* d_ws, size_t ws_size,
                              hipStream_t stream) {
    (void)in_sizes; (void)n_in; (void)out_size;
    const float* Q = (const float*)d_in[0];
    const float* K = (const float*)d_in[1];
    const float* V = (const float*)d_in[2];
    const int*  VLp = (const int*)d_in[3];
    float* O = (float*)d_out;

    const size_t kv_elems = (size_t)NB * SKn * DHn;          // 2M
    const size_t rows     = (size_t)NB * SQn;                // 32768
    // ws: Kh f16 | VTh f16 | Opart f16 (KS*rows*64) | lpart f32 (KS*rows)
    const size_t off_Kh = 0;
    const size_t off_VT = kv_elems * sizeof(_Float16);
    const size_t off_Op = off_VT + kv_elems * sizeof(_Float16);
    const size_t off_lp = off_Op + (size_t)KS * rows * DHn * sizeof(_Float16);
    const size_t need   = off_lp + (size_t)KS * rows * sizeof(float);

    if (ws_size >= need) {
        _Float16* Kh    = (_Float16*)((char*)d_ws + off_Kh);
        _Float16* VTh   = (_Float16*)((char*)d_ws + off_VT);
        _Float16* Opart = (_Float16*)((char*)d_ws + off_Op);
        float* lpart    = (float*)((char*)d_ws + off_lp);
        hipLaunchKernelGGL(prep_kernel, dim3(SKn / 64, NB), dim3(256), 0, stream, K, V, Kh, VTh);
        // grid: 16 b x 4 ks x 8 qb = 512 blocks x 8 waves (256 q/block)
        hipLaunchKernelGGL(attn_db, dim3(NB * KS * (SQn / 256)), dim3(512), 0, stream,
                           Q, Kh, VTh, VLp, Opart, lpart);
        hipLaunchKernelGGL(merge_kernel, dim3((NB * SQn * DHn / 4) / 256), dim3(256), 0, stream,
                           Opart, lpart, VLp, O);
    } else {
        hipLaunchKernelGGL(attn_fwd, dim3(NB * (SQn / 64)), dim3(256), 0, stream, Q, K, V, VLp, O);
    }
}